// Round 1
// baseline (407.856 us; speedup 1.0000x reference)
//
#include <hip/hip_runtime.h>
#include <hip/hip_bf16.h>

// coif4 decomposition low-pass filter (L=24), fp32
constexpr int L = 24;
__device__ __constant__ float DEC_LO[L] = {
    -1.7849850030882614e-06f, -3.2596802368833675e-06f, 3.1229875865345646e-05f,
    6.233903446100713e-05f, -0.00025997455248771324f, -0.0005890207562443383f,
    0.0012665619292989445f, 0.003751436157278457f, -0.00565828668661072f,
    -0.015211731527946259f, 0.025082261844864097f, 0.03933442712333749f,
    -0.09622044203398798f, -0.06662747426342504f, 0.4343860564914685f,
    0.782238930920499f, 0.41530840703043026f, -0.05607731331675481f,
    -0.08126669968087875f, 0.026682300156053072f, 0.016068943964776348f,
    -0.0073461663276420935f, -0.0016294920126017326f, 0.0008923136685823146f
};

// g0[m] = DEC_LO[23-m] (reconstruction low), g1[m] = (-1)^m DEC_LO[m] (reconstruction high)
__device__ __forceinline__ float g0f(int m) { return DEC_LO[23 - m]; }
__device__ __forceinline__ float g1f(int m) { return (m & 1) ? -DEC_LO[m] : DEC_LO[m]; }

// 1-D periodic inverse DWT along the H (row-index) axis.
// low/high: (C, n, W) logically (strides given); out: (C, 2n, W).
// out[2q]   = sum_t g0[2t+1]*L[(q+5-t) mod n] + g1[2t+1]*H[(q+5-t) mod n]
// out[2q+1] = sum_t g0[2t]  *L[(q+6-t) mod n] + g1[2t]  *H[(q+6-t) mod n]
__global__ void colpass_kernel(const float* __restrict__ low, const float* __restrict__ high,
                               float sLow, float sHigh,
                               int lowCS, int highCS, int n, int W,
                               float* __restrict__ out)
{
    int x = blockIdx.x * 64 + threadIdx.x;
    int q = blockIdx.y * blockDim.y + threadIdx.y;
    int c = blockIdx.z;
    int mask = n - 1;
    const float* lp = low + (size_t)c * lowCS + x;
    const float* hp = high + (size_t)c * highCS + x;
    float a0 = 0.f, a1 = 0.f;
#pragma unroll
    for (int s = 0; s <= 12; ++s) {
        int r = (q + 6 - s) & mask;
        float lv = sLow * lp[(size_t)r * W];
        float hv = sHigh * hp[(size_t)r * W];
        if (s >= 1)  a0 = fmaf(g0f(2 * s - 1), lv, fmaf(g1f(2 * s - 1), hv, a0));
        if (s <= 11) a1 = fmaf(g0f(2 * s), lv, fmaf(g1f(2 * s), hv, a1));
    }
    size_t ob = ((size_t)c * (2 * n) + 2 * q) * W + x;
    out[ob] = a0;
    out[ob + W] = a1;
}

// 1-D periodic inverse DWT along the W (last) axis.
// lo/hi: (C, N, n), N = 2n; out: (C, N, N).
__global__ void rowpass_kernel(const float* __restrict__ lo, const float* __restrict__ hi,
                               int n, float* __restrict__ out)
{
    int q = blockIdx.x * 64 + threadIdx.x;
    int y = blockIdx.y * blockDim.y + threadIdx.y;
    int c = blockIdx.z;
    int N = 2 * n, mask = n - 1;
    const float* lp = lo + ((size_t)c * N + y) * n;
    const float* hp = hi + ((size_t)c * N + y) * n;
    float a0 = 0.f, a1 = 0.f;
#pragma unroll
    for (int s = 0; s <= 12; ++s) {
        int r = (q + 6 - s) & mask;
        float lv = lp[r];
        float hv = hp[r];
        if (s >= 1)  a0 = fmaf(g0f(2 * s - 1), lv, fmaf(g1f(2 * s - 1), hv, a0));
        if (s <= 11) a1 = fmaf(g0f(2 * s), lv, fmaf(g1f(2 * s), hv, a1));
    }
    float2* op = (float2*)(out + ((size_t)c * N + y) * N + 2 * q);
    *op = make_float2(a0, a1);
}

// (32, 1048576) -> (1048576, 32), LDS tiled, conflict-free
__global__ void chw2hwc_kernel(const float* __restrict__ src, float* __restrict__ dst)
{
    __shared__ float tile[32][65];
    int base = blockIdx.x * 64;
    int tid = threadIdx.x;
#pragma unroll
    for (int k = 0; k < 8; ++k) {
        int idx = k * 256 + tid;
        int c = idx >> 6, x = idx & 63;
        tile[c][x] = src[(size_t)c * 1048576 + base + x];
    }
    __syncthreads();
#pragma unroll
    for (int k = 0; k < 8; ++k) {
        int idx = k * 256 + tid;
        int pix = idx >> 5, c = idx & 31;
        dst[(size_t)(base + pix) * 32 + c] = tile[c][pix];
    }
}

// plane: HWC (1024,1024,32); pts: (npts,2); out: (npts,32)
__global__ void sample_kernel(const float* __restrict__ pts, const float* __restrict__ plane,
                              float* __restrict__ out, int npts)
{
    int tid = blockIdx.x * 256 + threadIdx.x;
    int p = tid >> 5, c = tid & 31;
    if (p >= npts) return;
    float px = pts[2 * p + 0];
    float py = pts[2 * p + 1];
    float xf = fminf(fmaxf((px + 1.f) * 0.5f * 1023.f, 0.f), 1023.f);
    float yf = fminf(fmaxf((py + 1.f) * 0.5f * 1023.f, 0.f), 1023.f);
    int x0 = (int)xf, y0 = (int)yf;           // xf,yf >= 0: trunc == floor
    int x1 = min(x0 + 1, 1023), y1 = min(y0 + 1, 1023);
    float wx = xf - (float)x0, wy = yf - (float)y0;
    const float* row0 = plane + ((size_t)y0 * 1024) * 32 + c;
    const float* row1 = plane + ((size_t)y1 * 1024) * 32 + c;
    float v00 = row0[(size_t)x0 * 32], v01 = row0[(size_t)x1 * 32];
    float v10 = row1[(size_t)x0 * 32], v11 = row1[(size_t)x1 * 32];
    float r = (v00 * (1.f - wx) + v01 * wx) * (1.f - wy)
            + (v10 * (1.f - wx) + v11 * wx) * wy;
    out[(size_t)p * 32 + c] = r;
}

extern "C" void kernel_launch(void* const* d_in, const int* in_sizes, int n_in,
                              void* d_out, int out_size, void* d_ws, size_t ws_size,
                              hipStream_t stream)
{
    const float* pts = (const float*)d_in[0];
    const float* yl  = (const float*)d_in[1];
    const float* yh0 = (const float*)d_in[2]; // (32,3,512,512), scale 0.2, level 3
    const float* yh1 = (const float*)d_in[3]; // (32,3,256,256), scale 0.4, level 2
    const float* yh2 = (const float*)d_in[4]; // (32,3,128,128), scale 0.6, level 1
    const int C = 32;
    const int npts = in_sizes[0] / 2;

    float* ws = (float*)d_ws;
    // Workspace layout (floats), liveness-aliased; total 67,108,864 floats = 256 MiB:
    //   [0,        16777216)  tmp_lo  (max C x 1024 x 512)   } later reused as planeHWC
    //   [16777216, 33554432)  tmp_hi                          }
    //   [33554432, 67108864)  planeCHW (C x 1024 x 1024); ll buffers live here early
    float* tmp_lo   = ws;
    float* tmp_hi   = ws + 16777216;
    float* planeCHW = ws + 33554432;
    float* llbuf    = planeCHW;   // ll1 (C,256,256) then ll2 (C,512,512); dead before planeCHW written
    float* planeHWC = ws;         // overlays tmps, which are dead after the level-3 rowpass

    dim3 cb(64, 4, 1);

    // ---- Level 1: n=128 -> 256. details yh2 * 0.6, ll = yl * 1.0
    {
        int n = 128, nn = n * n;
        dim3 cg(n / 64, n / 4, C);
        colpass_kernel<<<cg, cb, 0, stream>>>(yl, yh2 + 0 * nn, 1.0f, 0.6f, nn, 3 * nn, n, n, tmp_lo);
        colpass_kernel<<<cg, cb, 0, stream>>>(yh2 + 1 * nn, yh2 + 2 * nn, 0.6f, 0.6f, 3 * nn, 3 * nn, n, n, tmp_hi);
        dim3 rg(n / 64, (2 * n) / 4, C);
        rowpass_kernel<<<rg, cb, 0, stream>>>(tmp_lo, tmp_hi, n, llbuf);
    }
    // ---- Level 2: n=256 -> 512. details yh1 * 0.4
    {
        int n = 256, nn = n * n;
        dim3 cg(n / 64, n / 4, C);
        colpass_kernel<<<cg, cb, 0, stream>>>(llbuf, yh1 + 0 * nn, 1.0f, 0.4f, nn, 3 * nn, n, n, tmp_lo);
        colpass_kernel<<<cg, cb, 0, stream>>>(yh1 + 1 * nn, yh1 + 2 * nn, 0.4f, 0.4f, 3 * nn, 3 * nn, n, n, tmp_hi);
        dim3 rg(n / 64, (2 * n) / 4, C);
        rowpass_kernel<<<rg, cb, 0, stream>>>(tmp_lo, tmp_hi, n, llbuf);
    }
    // ---- Level 3: n=512 -> 1024. details yh0 * 0.2
    {
        int n = 512, nn = n * n;
        dim3 cg(n / 64, n / 4, C);
        colpass_kernel<<<cg, cb, 0, stream>>>(llbuf, yh0 + 0 * nn, 1.0f, 0.2f, nn, 3 * nn, n, n, tmp_lo);
        colpass_kernel<<<cg, cb, 0, stream>>>(yh0 + 1 * nn, yh0 + 2 * nn, 0.2f, 0.2f, 3 * nn, 3 * nn, n, n, tmp_hi);
        dim3 rg(n / 64, (2 * n) / 4, C);
        rowpass_kernel<<<rg, cb, 0, stream>>>(tmp_lo, tmp_hi, n, planeCHW);
    }
    // ---- CHW -> HWC transpose (for 128B-contiguous per-pixel channel reads)
    chw2hwc_kernel<<<16384, 256, 0, stream>>>(planeCHW, planeHWC);
    // ---- Bilinear sampling
    sample_kernel<<<(npts * 32) / 256, 256, 0, stream>>>(pts, planeHWC, (float*)d_out, npts);
}